// Round 11
// baseline (558.725 us; speedup 1.0000x reference)
//
#include <hip/hip_runtime.h>
#include <hip/hip_bf16.h>

#define N_USERS_C 100000
#define N_ITEMS_C 20000
#define N_NODES_C 120000
#define E_TOT_C   400000
#define D_IN_C    192
#define HID_C     256
#define NEG_C     0.2f
#define CLAMP_C   1000.0f
#define KPAD_C    1152   // 1148 padded to multiple of 32
#define NB_SCAN   ((N_NODES_C + 255) / 256)   // 469 scan blocks
#define NB_EDGE   ((E_TOT_C + 255) / 256)     // 1563 edge blocks
#define NB_GEMM   (N_NODES_C / 64)            // 1875 gemm blocks
#define NB_G1U    1562                        // pure-user gemm1 blocks (kmax=64)
#define NB_G1M    (NB_GEMM - NB_G1U)          // 313 movie/mixed gemm1 blocks
#define ROWE      40     // LDS row length in shorts: 32 k-elems + 8 pad (80B, 16B-aligned)
#define NT_MOV    313    // ceil(20000/64) row tiles
#define KSPLIT    4
#define KCH       288    // 1152 / KSPLIT
#define NSTEP_MOV (KCH / 32)                  // 9

typedef __attribute__((ext_vector_type(8))) short bfrag;
typedef __attribute__((ext_vector_type(4))) float ffrag;

__device__ __forceinline__ float bf2f(unsigned short u){
  return __uint_as_float(((unsigned)u) << 16);
}
__device__ __forceinline__ float ldf(const void* p, long i, int isf32){
  return isf32 ? ((const float*)p)[i] : bf2f(((const unsigned short*)p)[i]);
}
__device__ __forceinline__ float sane(float v){
  return (v > -1e30f && v < 1e30f) ? v : 0.f;
}
__device__ __forceinline__ int clampsrc(int s){
  return s < 0 ? 0 : (s >= N_NODES_C ? N_NODES_C - 1 : s);
}
__device__ __forceinline__ short f2bs(float f){
  __hip_bfloat16 h = __float2bfloat16(f);
  return *reinterpret_cast<short*>(&h);
}

// ---------- dtype discriminator (inputs) ----------
__global__ __launch_bounds__(256) void detect_dtype(const unsigned short* __restrict__ ue,
                                                    int* __restrict__ flag){
  __shared__ int cnt[256];
  int tid = threadIdx.x; int c = 0;
  for (int i = tid; i < 8192; i += 256){
    unsigned e = (ue[i] >> 7) & 0xFFu;
    if (e >= 129u) c++;
  }
  cnt[tid] = c; __syncthreads();
  if (tid == 0){
    int s = 0;
    for (int i = 0; i < 256; i++) s += cnt[i];
    *flag = (s > 100) ? 1 : 0;
  }
}

// ---------- MEGA-PREP: one launch, 8-elems/thread vectorized (G13) ----------
struct PrepArgs {
  const void *ue, *ie;
  const void *gW1, *gb1, *gW2, *gb2, *tW1, *tb1, *tW2, *tb2;
  const void *Ws1, *Wd1, *as1, *ad1, *b1, *Ws2, *Wd2, *as2, *ad2, *b2;
  __hip_bfloat16 *x, *Bt1, *Bt2, *W1t, *W2t, *b1c, *b2c, *bg1, *bg2;
  int *deg, *cursor;
  const int* flag;
};

#define NB_UEMB  3125   // 100000*64 /8 /256
#define NB_UZERO 2      // 32 rows x 128 cols /8 /256
#define NB_MOVE  625    // 20000*64 /8 /256
#define NB_BT1   204    // 272*192 /256 (scalar)
#define NB_BT2   272    // 272*256 /256 (scalar)
#define NB_W1T   72     // 128*1152 /8 /256
#define NB_W2T   8      // 128*128 /8 /256
#define NB_ZERO  235    // 240000 ints /4 /256
#define NB_PREP (NB_UEMB+NB_UZERO+NB_MOVE+NB_BT1+NB_BT2+NB_W1T+NB_W2T+1+NB_ZERO)

__global__ __launch_bounds__(256) void mega_prep(PrepArgs a){
  int b = blockIdx.x, tid = threadIdx.x;
  int f32 = *a.flag;
  if (b < NB_UEMB) {                     // x user rows cols 0..63, 8 elems/thread
    int idx = b * 256 + tid;
    int n = idx >> 3, c0 = (idx & 7) * 8;
    union { short s[8]; float4 f; } u;
    if (f32) {
      const float* rf = (const float*)a.ue + (long)n * 64 + c0;
      float4 x0 = *(const float4*)rf, x1 = *(const float4*)(rf + 4);
      u.s[0]=f2bs(x0.x); u.s[1]=f2bs(x0.y); u.s[2]=f2bs(x0.z); u.s[3]=f2bs(x0.w);
      u.s[4]=f2bs(x1.x); u.s[5]=f2bs(x1.y); u.s[6]=f2bs(x1.z); u.s[7]=f2bs(x1.w);
    } else {
      u.f = *(const float4*)((const unsigned short*)a.ue + (long)n * 64 + c0);
    }
    *(float4*)(&a.x[(long)n * 192 + c0]) = u.f;
    return;
  }
  b -= NB_UEMB;
  if (b < NB_UZERO) {                    // boundary user rows 99968..99999, cols 64..191 = 0
    int idx = b * 256 + tid;
    int r = idx >> 4, c0 = 64 + (idx & 15) * 8;
    float4 z = {0.f, 0.f, 0.f, 0.f};
    *(float4*)(&a.x[(long)(99968 + r) * 192 + c0]) = z;
    return;
  }
  b -= NB_UZERO;
  if (b < NB_MOVE) {                     // x movie rows cols 0..63 = item_emb
    int idx = b * 256 + tid;
    int m = idx >> 3, c0 = (idx & 7) * 8;
    union { short s[8]; float4 f; } u;
    if (f32) {
      const float* rf = (const float*)a.ie + (long)m * 64 + c0;
      float4 x0 = *(const float4*)rf, x1 = *(const float4*)(rf + 4);
      u.s[0]=f2bs(x0.x); u.s[1]=f2bs(x0.y); u.s[2]=f2bs(x0.z); u.s[3]=f2bs(x0.w);
      u.s[4]=f2bs(x1.x); u.s[5]=f2bs(x1.y); u.s[6]=f2bs(x1.z); u.s[7]=f2bs(x1.w);
    } else {
      u.f = *(const float4*)((const unsigned short*)a.ie + (long)m * 64 + c0);
    }
    *(float4*)(&a.x[(long)(N_USERS_C + m) * 192 + c0]) = u.f;
    return;
  }
  b -= NB_MOVE;
  if (b < NB_BT1) {                      // Bt1 (272 x 192)
    int idx = b * 256 + tid;
    int col = idx / 192, k = idx - col * 192;
    float v;
    if (col < 256) v = ldf(a.Ws1, k * 256 + col, f32);
    else if (col < 264) {
      int h = col - 256; float s = 0.f;
      for (int c = 0; c < 32; c++)
        s += ldf(a.Ws1, k * 256 + h * 32 + c, f32) * ldf(a.as1, h * 32 + c, f32);
      v = s;
    } else {
      int h = col - 264; float s = 0.f;
      for (int c = 0; c < 32; c++)
        s += ldf(a.Wd1, k * 256 + h * 32 + c, f32) * ldf(a.ad1, h * 32 + c, f32);
      v = s;
    }
    a.Bt1[col * 192 + k] = __float2bfloat16(v);
    return;
  }
  b -= NB_BT1;
  if (b < NB_BT2) {                      // Bt2 (272 x 256), H=1, C=256
    int idx = b * 256 + tid;
    int col = idx / 256, k = idx & 255;
    float v;
    if (col < 256) v = ldf(a.Ws2, k * 256 + col, f32);
    else if (col == 256) {
      float s = 0.f;
      for (int c = 0; c < 256; c++)
        s += ldf(a.Ws2, k * 256 + c, f32) * ldf(a.as2, c, f32);
      v = s;
    } else if (col == 257) {
      float s = 0.f;
      for (int c = 0; c < 256; c++)
        s += ldf(a.Wd2, k * 256 + c, f32) * ldf(a.ad2, c, f32);
      v = s;
    } else v = 0.f;
    a.Bt2[col * 256 + k] = __float2bfloat16(v);
    return;
  }
  b -= NB_BT2;
  if (b < NB_W1T) {                      // W1t (128 x 1152), 8 elems/thread
    int idx = b * 256 + tid;
    int n = idx / 144, c8 = idx - n * 144;
    int k0 = c8 * 8;
    union { short s[8]; float4 f; } u;
#pragma unroll
    for (int j = 0; j < 8; j++) {
      int k = k0 + j; float v = 0.f;
      if (n < 64) { if (k < 20) v = ldf(a.gW1, k * 64 + n, f32); }
      else        { if (k >= 20 && k < 1148) v = ldf(a.tW1, (k - 20) * 64 + (n - 64), f32); }
      u.s[j] = f2bs(v);
    }
    *(float4*)(&a.W1t[(long)n * 1152 + k0]) = u.f;
    return;
  }
  b -= NB_W1T;
  if (b < NB_W2T) {                      // W2t (128 x 128) blockdiag, 8 elems/thread
    int idx = b * 256 + tid;
    int n = idx >> 4, k0 = (idx & 15) * 8;
    union { short s[8]; float4 f; } u;
#pragma unroll
    for (int j = 0; j < 8; j++) {
      int k = k0 + j; float v = 0.f;
      if (n < 64) { if (k < 64)  v = ldf(a.gW2, k * 64 + n, f32); }
      else        { if (k >= 64) v = ldf(a.tW2, (k - 64) * 64 + (n - 64), f32); }
      u.s[j] = f2bs(v);
    }
    *(float4*)(&a.W2t[n * 128 + k0]) = u.f;
    return;
  }
  b -= NB_W2T;
  if (b < 1) {                           // all bias vectors
    int i = tid;
    if (i < 64)       a.b1c[i] = __float2bfloat16(ldf(a.gb1, i, f32));
    else if (i < 128) a.b1c[i] = __float2bfloat16(ldf(a.tb1, i - 64, f32));
    else if (i < 192) a.b2c[i - 128] = __float2bfloat16(ldf(a.gb2, i - 128, f32));
    else              a.b2c[i - 128] = __float2bfloat16(ldf(a.tb2, i - 192, f32));
    a.bg1[tid] = __float2bfloat16(ldf(a.b1, tid, f32));
    a.bg2[tid] = __float2bfloat16(ldf(a.b2, tid, f32));
    return;
  }
  b -= 1;
  {                                      // zero deg + cursor, int4/thread
    int i0 = (b * 256 + tid) * 4;
    if (i0 < 2 * N_NODES_C) {
      int4 z = {0, 0, 0, 0};
      if (i0 < N_NODES_C) *(int4*)(a.deg + i0) = z;
      else                *(int4*)(a.cursor + (i0 - N_NODES_C)) = z;
    }
  }
}

// ---------- device bodies (smem passed in so merged kernels share one buffer) -------

// movie layer 1 K-split partial with T14 async-stage: next k-step's A+B loads are
// issued BEFORE current compute (same 2 barriers; HBM latency hides under MFMA).
__device__ void movie_k_body(int bid, const void* __restrict__ rawA, int f32v,
                             const __hip_bfloat16* __restrict__ W1t,
                             float* __restrict__ part,
                             short* __restrict__ Bls, short* __restrict__ Als){
  int tid = threadIdx.x;
  int wave = tid >> 6, lane = tid & 63, l15 = lane & 15, quad = lane >> 4;
  int tile = bid % NT_MOV, split = bid / NT_MOV;
  int rowbase_blk = tile * 64;
  int rowbase = rowbase_blk + wave * 16;
  ffrag acc[8];
#pragma unroll
  for (int i = 0; i < 8; i++) acc[i] = (ffrag){0.f, 0.f, 0.f, 0.f};
  const short* Bs = (const short*)W1t;
  int sr = tid >> 2, sc = tid & 3;
  int arow_st = rowbase_blk + sr; if (arow_st >= N_ITEMS_C) arow_st = N_ITEMS_C - 1;
  int r0 = tid >> 2, r1 = r0 + 64, cb = (tid & 3) * 8;   // B rows for tasks tid, tid+256
  int kbeg = split * KCH;

  auto loadA = [&](int k0) -> float4 {
    int kc = k0 + sc * 8;
    union { short s[8]; float4 f; } u;
    long base = (long)arow_st * 1148 + kc;
    if (kc + 8 <= 1148) {
      if (f32v) {
        const float* rf = (const float*)rawA + base;
        float4 x0 = *(const float4*)rf, x1 = *(const float4*)(rf + 4);
        u.s[0]=f2bs(x0.x); u.s[1]=f2bs(x0.y); u.s[2]=f2bs(x0.z); u.s[3]=f2bs(x0.w);
        u.s[4]=f2bs(x1.x); u.s[5]=f2bs(x1.y); u.s[6]=f2bs(x1.z); u.s[7]=f2bs(x1.w);
      } else {
        const unsigned short* rs = (const unsigned short*)rawA + base;
        ushort4 a0 = *(const ushort4*)rs, a1 = *(const ushort4*)(rs + 4);
        u.s[0]=(short)a0.x; u.s[1]=(short)a0.y; u.s[2]=(short)a0.z; u.s[3]=(short)a0.w;
        u.s[4]=(short)a1.x; u.s[5]=(short)a1.y; u.s[6]=(short)a1.z; u.s[7]=(short)a1.w;
      }
    } else {
#pragma unroll
      for (int j = 0; j < 8; j++) {
        float v = (kc + j < 1148) ? ldf(rawA, base + j, f32v) : 0.f;
        u.s[j] = f2bs(v);
      }
    }
    return u.f;
  };

  // prologue: step-0 loads in regs
  float4 aR = loadA(kbeg);
  float4 bR0 = *(const float4*)(Bs + (long)r0 * KPAD_C + kbeg + cb);
  float4 bR1 = *(const float4*)(Bs + (long)r1 * KPAD_C + kbeg + cb);

  for (int s = 0; s < NSTEP_MOV; s++) {
    // write current step's regs to LDS (prev reads protected by trailing barrier)
    *(float4*)(&Als[sr * ROWE + sc * 8]) = aR;
    *(float4*)(&Bls[r0 * ROWE + cb]) = bR0;
    *(float4*)(&Bls[r1 * ROWE + cb]) = bR1;
    __syncthreads();
    if (s + 1 < NSTEP_MOV) {            // issue next step's loads; latency hides below
      int kn = kbeg + (s + 1) * 32;
      aR = loadA(kn);
      bR0 = *(const float4*)(Bs + (long)r0 * KPAD_C + kn + cb);
      bR1 = *(const float4*)(Bs + (long)r1 * KPAD_C + kn + cb);
    }
    int koff = quad * 8;
    bfrag af = *(const bfrag*)(&Als[(wave * 16 + l15) * ROWE + koff]);
#pragma unroll
    for (int nt = 0; nt < 8; nt++) {
      bfrag bf = *(const bfrag*)(&Bls[(nt * 16 + l15) * ROWE + koff]);
      acc[nt] = __builtin_amdgcn_mfma_f32_16x16x32_bf16(af, bf, acc[nt], 0, 0, 0);
    }
    __syncthreads();
  }
  float* pb = part + (long)split * (N_ITEMS_C * 128);
#pragma unroll
  for (int reg = 0; reg < 4; reg++) {
    int grow = rowbase + quad * 4 + reg;
    if (grow >= N_ITEMS_C) continue;
#pragma unroll
    for (int nt = 0; nt < 8; nt++)
      pb[(long)grow * 128 + nt * 16 + l15] = acc[nt][reg];
  }
}

// movie layer 2: reduce KSPLIT partials + bias1 + relu in A-staging.
__device__ void movie2_body(int bid, const float* __restrict__ part,
                            const __hip_bfloat16* __restrict__ b1c,
                            const __hip_bfloat16* __restrict__ W2t,
                            const __hip_bfloat16* __restrict__ b2c,
                            __hip_bfloat16* __restrict__ out,
                            short* __restrict__ Bls, short* __restrict__ Als){
  int tid = threadIdx.x;
  int wave = tid >> 6, lane = tid & 63, l15 = lane & 15, quad = lane >> 4;
  int rowbase_blk = bid * 64;
  int rowbase = rowbase_blk + wave * 16;
  ffrag acc[8];
#pragma unroll
  for (int i = 0; i < 8; i++) acc[i] = (ffrag){0.f, 0.f, 0.f, 0.f};
  const short* Bs = (const short*)W2t;
  int sr = tid >> 2, sc = tid & 3;
  int arow_st = rowbase_blk + sr; if (arow_st >= N_ITEMS_C) arow_st = N_ITEMS_C - 1;
  for (int k0 = 0; k0 < 128; k0 += 32) {
    __syncthreads();
    for (int t = tid; t < 512; t += 256) {
      int r = t >> 2, c = t & 3;
      *(float4*)(&Bls[r * ROWE + c * 8]) =
          *(const float4*)(Bs + (long)r * 128 + k0 + c * 8);
    }
    int kc = k0 + sc * 8;
    float vs[8];
#pragma unroll
    for (int j = 0; j < 8; j++) vs[j] = __bfloat162float(b1c[kc + j]);
    long base = (long)arow_st * 128 + kc;
#pragma unroll
    for (int s = 0; s < KSPLIT; s++) {
      const float* p = part + (long)s * (N_ITEMS_C * 128) + base;
      float4 q0 = *(const float4*)p, q1 = *(const float4*)(p + 4);
      vs[0] += q0.x; vs[1] += q0.y; vs[2] += q0.z; vs[3] += q0.w;
      vs[4] += q1.x; vs[5] += q1.y; vs[6] += q1.z; vs[7] += q1.w;
    }
    union { short s[8]; float4 f; } u;
#pragma unroll
    for (int j = 0; j < 8; j++) u.s[j] = f2bs(fmaxf(vs[j], 0.f));
    *(float4*)(&Als[sr * ROWE + sc * 8]) = u.f;
    __syncthreads();
    int koff = quad * 8;
    bfrag af = *(const bfrag*)(&Als[(wave * 16 + l15) * ROWE + koff]);
#pragma unroll
    for (int nt = 0; nt < 8; nt++) {
      bfrag bf = *(const bfrag*)(&Bls[(nt * 16 + l15) * ROWE + koff]);
      acc[nt] = __builtin_amdgcn_mfma_f32_16x16x32_bf16(af, bf, acc[nt], 0, 0, 0);
    }
  }
#pragma unroll
  for (int reg = 0; reg < 4; reg++) {
    int grow = rowbase + quad * 4 + reg;
    if (grow >= N_ITEMS_C) continue;
#pragma unroll
    for (int nt = 0; nt < 8; nt++) {
      float v = acc[nt][reg] + __bfloat162float(b2c[nt * 16 + l15]);
      out[(long)grow * D_IN_C + 64 + nt * 16 + l15] = __float2bfloat16(v);
    }
  }
}

// gemm_fused body with T14 A-prefetch: next k-step's A load issued before compute
// (B is L2-hot Bt1/Bt2, stays synchronous). ukmax per R5 (user rows: cols>=64 are 0).
__device__ void gemm_fused_body(int bid,
    const __hip_bfloat16* __restrict__ A, const __hip_bfloat16* __restrict__ Bt,
    __hip_bfloat16* __restrict__ Hout, float* __restrict__ als, float* __restrict__ ald,
    int K, int natt, int ukmax,
    short* __restrict__ Bls, short* __restrict__ Als){
  int tid = threadIdx.x;
  int wave = tid >> 6, lane = tid & 63, l15 = lane & 15, quad = lane >> 4;
  int rowbase_blk = bid * 64;
  int rowbase = rowbase_blk + wave * 16;
  int kmax = (rowbase_blk + 64 <= N_USERS_C) ? ukmax : K;
  ffrag acc[17];
#pragma unroll
  for (int i = 0; i < 17; i++) acc[i] = (ffrag){0.f, 0.f, 0.f, 0.f};
  const short* As = (const short*)A;
  const short* Bs = (const short*)Bt;
  int sr = tid >> 2, sc = tid & 3;
  long arow = (long)(rowbase_blk + sr) * K;
  float4 aR = *(const float4*)(As + arow + sc * 8);   // prologue A(k0=0)
  for (int k0 = 0; k0 < kmax; k0 += 32) {
    *(float4*)(&Als[sr * ROWE + sc * 8]) = aR;        // prev reads done (trailing barrier)
    for (int t = tid; t < 1088; t += 256) {
      int r = t >> 2, c = t & 3;
      *(float4*)(&Bls[r * ROWE + c * 8]) = *(const float4*)(Bs + (long)r * K + k0 + c * 8);
    }
    __syncthreads();
    if (k0 + 32 < kmax)
      aR = *(const float4*)(As + arow + k0 + 32 + sc * 8);  // overlaps compute below
    int koff = quad * 8;
    bfrag af = *(const bfrag*)(&Als[(wave * 16 + l15) * ROWE + koff]);
#pragma unroll
    for (int nt = 0; nt < 17; nt++) {
      bfrag bf = *(const bfrag*)(&Bls[(nt * 16 + l15) * ROWE + koff]);
      acc[nt] = __builtin_amdgcn_mfma_f32_16x16x32_bf16(af, bf, acc[nt], 0, 0, 0);
    }
    __syncthreads();
  }
  int col = l15;
#pragma unroll
  for (int reg = 0; reg < 4; reg++) {
    int grow = rowbase + quad * 4 + reg;
    long obase = (long)grow * 256;
#pragma unroll
    for (int nt = 0; nt < 16; nt++)
      Hout[obase + nt * 16 + col] = __float2bfloat16(acc[nt][reg]);
    float v = acc[16][reg];
    if (col < natt) als[grow * natt + col] = v;
    else if (col < 2 * natt) ald[grow * natt + (col - natt)] = v;
  }
}

__device__ void deg_count_body(int e, const int* __restrict__ ei, int* __restrict__ deg){
  if (e >= E_TOT_C) return;
  int dst = ei[E_TOT_C + e];
  if (dst >= 0 && dst < N_NODES_C) atomicAdd(&deg[dst], 1);
}

__device__ void deg_bsum_body(int bid, const int* __restrict__ deg, int* __restrict__ bsum){
  int i = bid * 256 + threadIdx.x;
  int v = (i < N_NODES_C) ? deg[i] : 0;
#pragma unroll
  for (int o = 32; o > 0; o >>= 1) v += __shfl_down(v, o, 64);
  __shared__ int ws[4];
  int wave = threadIdx.x >> 6, lane = threadIdx.x & 63;
  if (lane == 0) ws[wave] = v;
  __syncthreads();
  if (threadIdx.x == 0) bsum[bid] = ws[0] + ws[1] + ws[2] + ws[3];
}

__device__ void scatter_body(int e, const int* __restrict__ ei, const int* __restrict__ ptrn,
                             int* __restrict__ cursor, int* __restrict__ elist_src){
  if (e >= E_TOT_C) return;
  int dst = ei[E_TOT_C + e];
  if (dst < 0 || dst >= N_NODES_C) return;
  int pos = atomicAdd(&cursor[dst], 1);
  elist_src[ptrn[dst] + pos] = ei[e];
}

// ---------- merged kernels (block-range dispatch; each block takes ONE path) ----------
// Stage 3: [movie_k (1252) || gemm1 user blocks (1562) || deg_count (1563)] = 4377.
// All three depend only on mega_prep; gemm's MFMA waves fill movie_k's idle pipes.
#define NB_BIG (NT_MOV * KSPLIT + NB_G1U + NB_EDGE)
__global__ __launch_bounds__(256) void fused_stage3(
    const void* __restrict__ rawA, const int* __restrict__ flag,
    const __hip_bfloat16* __restrict__ W1t, float* __restrict__ part,
    const __hip_bfloat16* __restrict__ x, const __hip_bfloat16* __restrict__ Bt1,
    __hip_bfloat16* __restrict__ hs, float* __restrict__ als, float* __restrict__ ald,
    const int* __restrict__ ei, int* __restrict__ deg){
  __shared__ short smem[(272 + 64) * ROWE];   // union: gemm 26.25KB > movie 15KB
  int b = blockIdx.x;
  if (b < NT_MOV * KSPLIT)
    movie_k_body(b, rawA, *flag, W1t, part, smem, smem + 128 * ROWE);
  else if (b < NT_MOV * KSPLIT + NB_G1U)
    gemm_fused_body(b - NT_MOV * KSPLIT, x, Bt1, hs, als, ald, 192, 8, 64,
                    smem, smem + 272 * ROWE);
  else
    deg_count_body((b - NT_MOV * KSPLIT - NB_G1U) * 256 + threadIdx.x, ei, deg);
}

#define NB_KB (NT_MOV + NB_SCAN)            // 313 + 469 = 782
__global__ __launch_bounds__(256) void movie2_bsum(
    const float* __restrict__ part, const __hip_bfloat16* __restrict__ b1c,
    const __hip_bfloat16* __restrict__ W2t, const __hip_bfloat16* __restrict__ b2c,
    __hip_bfloat16* __restrict__ out,
    const int* __restrict__ deg, int* __restrict__ bsum){
  __shared__ short smem[192 * ROWE];          // movie2: 15KB
  int b = blockIdx.x;
  if (b < NT_MOV) movie2_body(b, part, b1c, W2t, b2c, out, smem, smem + 128 * ROWE);
  else deg_bsum_body(b - NT_MOV, deg, bsum);
}

// Stage 7: [gemm1 movie/mixed blocks (313) || scatter (1563)].
#define NB_S7 (NB_G1M + NB_EDGE)
__global__ __launch_bounds__(256) void gemm1mov_scatter(
    const __hip_bfloat16* __restrict__ A, const __hip_bfloat16* __restrict__ Bt,
    __hip_bfloat16* __restrict__ Hout, float* __restrict__ als, float* __restrict__ ald,
    const int* __restrict__ ei, const int* __restrict__ ptrn,
    int* __restrict__ cursor, int* __restrict__ elist_src){
  __shared__ short smem[(272 + 64) * ROWE];
  int b = blockIdx.x;
  if (b < NB_G1M)
    gemm_fused_body(NB_G1U + b, A, Bt, Hout, als, ald, 192, 8, 64,
                    smem, smem + 272 * ROWE);
  else
    scatter_body((b - NB_G1M) * 256 + threadIdx.x, ei, ptrn, cursor, elist_src);
}

// standalone gemm_fused for layer 2
__global__ __launch_bounds__(256) void gemm_fused(
    const __hip_bfloat16* __restrict__ A, const __hip_bfloat16* __restrict__ Bt,
    __hip_bfloat16* __restrict__ Hout, float* __restrict__ als, float* __restrict__ ald,
    int K, int natt, int ukmax){
  __shared__ short smem[(272 + 64) * ROWE];
  gemm_fused_body(blockIdx.x, A, Bt, Hout, als, ald, K, natt, ukmax,
                  smem, smem + 272 * ROWE);
}

// Stage 2: single-block Hillis-Steele scan of 469 block sums -> exclusive offsets.
__global__ __launch_bounds__(512) void bsum_scan(int* __restrict__ bsum,
                                                 int* __restrict__ ptrn){
  __shared__ int sm[512];
  int t = threadIdx.x;
  int v = (t < NB_SCAN) ? bsum[t] : 0;
  sm[t] = v;
  __syncthreads();
  for (int o = 1; o < 512; o <<= 1) {
    int add = (t >= o) ? sm[t - o] : 0;
    __syncthreads();
    sm[t] += add;
    __syncthreads();
  }
  int excl = (t == 0) ? 0 : sm[t - 1];
  if (t < NB_SCAN) bsum[t] = excl;
  if (t == NB_SCAN - 1) ptrn[N_NODES_C] = sm[t];
}

// Stage 3: in-block exclusive scan + block offset -> ptrn.
__global__ __launch_bounds__(256) void deg_scan_final(const int* __restrict__ deg,
                                                      const int* __restrict__ bexcl,
                                                      int* __restrict__ ptrn){
  __shared__ int sm[256];
  int i = blockIdx.x * 256 + threadIdx.x;
  int t = threadIdx.x;
  int v = (i < N_NODES_C) ? deg[i] : 0;
  sm[t] = v;
  __syncthreads();
  for (int o = 1; o < 256; o <<= 1) {
    int add = (t >= o) ? sm[t - o] : 0;
    __syncthreads();
    sm[t] += add;
    __syncthreads();
  }
  int excl = (t == 0) ? 0 : sm[t - 1];
  if (i < N_NODES_C) ptrn[i] = bexcl[blockIdx.x] + excl;
}

// ---------- layer 1: online-softmax aggregation, 2-deep software-pipelined gathers ----
__global__ __launch_bounds__(256) void aggregate1(
    const int* __restrict__ ptrn, const int* __restrict__ elist_src,
    const float* __restrict__ als, const float* __restrict__ ald,
    const __hip_bfloat16* __restrict__ hs, const __hip_bfloat16* __restrict__ bias,
    __hip_bfloat16* __restrict__ h1){
  int node = blockIdx.x * 4 + (threadIdx.x >> 6);
  if (node >= N_NODES_C) return;
  int lane = threadIdx.x & 63;
  int c0 = lane * 4;
  int h = lane >> 3;
  int beg = ptrn[node], end = ptrn[node + 1];
  float aldv = sane(ald[node * 8 + h]);
  float m = -1e30f;
  float wsum = 0.f, a0 = 0.f, a1 = 0.f, a2 = 0.f, a3 = 0.f;
  const unsigned short* hsu = (const unsigned short*)hs;
  float alsv_p = 0.f;
  ushort4 hv_p = {0, 0, 0, 0};
  int src_b = 0;
  if (beg < end) {
    int s0 = clampsrc(elist_src[beg]);
    alsv_p = als[(long)s0 * 8 + h];
    hv_p = *(const ushort4*)(hsu + (long)s0 * 256 + c0);
    if (beg + 1 < end) src_b = clampsrc(elist_src[beg + 1]);
  }
  for (int i = beg; i < end; i++) {
    float alsv = alsv_p;
    ushort4 hv = hv_p;
    if (i + 1 < end) {
      alsv_p = als[(long)src_b * 8 + h];
      hv_p = *(const ushort4*)(hsu + (long)src_b * 256 + c0);
    }
    if (i + 2 < end)
      src_b = clampsrc(elist_src[i + 2]);
    float ev = sane(alsv) + aldv;
    ev = ev > 0.f ? ev : NEG_C * ev;
    float mnew = fmaxf(m, ev);
    float corr = __expf(m - mnew);
    float w = __expf(ev - mnew);
    m = mnew;
    wsum = wsum * corr + w;
    a0 = a0 * corr + w * bf2f(hv.x); a1 = a1 * corr + w * bf2f(hv.y);
    a2 = a2 * corr + w * bf2f(hv.z); a3 = a3 * corr + w * bf2f(hv.w);
  }
  float inv = 1.f / (wsum + 1e-16f);
  float v0 = a0 * inv + __bfloat162float(bias[c0 + 0]);
  float v1 = a1 * inv + __bfloat162float(bias[c0 + 1]);
  float v2 = a2 * inv + __bfloat162float(bias[c0 + 2]);
  float v3 = a3 * inv + __bfloat162float(bias[c0 + 3]);
  v0 = v0 > 0.f ? v0 : (__expf(v0) - 1.f);
  v1 = v1 > 0.f ? v1 : (__expf(v1) - 1.f);
  v2 = v2 > 0.f ? v2 : (__expf(v2) - 1.f);
  v3 = v3 > 0.f ? v3 : (__expf(v3) - 1.f);
  v0 = fminf(fmaxf(v0, -CLAMP_C), CLAMP_C);
  v1 = fminf(fmaxf(v1, -CLAMP_C), CLAMP_C);
  v2 = fminf(fmaxf(v2, -CLAMP_C), CLAMP_C);
  v3 = fminf(fmaxf(v3, -CLAMP_C), CLAMP_C);
  long ob = (long)node * 256 + c0;
  h1[ob + 0] = __float2bfloat16(v0); h1[ob + 1] = __float2bfloat16(v1);
  h1[ob + 2] = __float2bfloat16(v2); h1[ob + 3] = __float2bfloat16(v3);
}

// ---------- layer 2: online softmax, pipelined, 1 head, f32 output (+tail fold) -----
__global__ __launch_bounds__(256) void aggregate2(
    const int* __restrict__ ptrn, const int* __restrict__ elist_src,
    const float* __restrict__ als, const float* __restrict__ ald,
    const __hip_bfloat16* __restrict__ hs, const __hip_bfloat16* __restrict__ bias,
    float* __restrict__ out, int out_size){
  if (blockIdx.x == 0 && threadIdx.x == 0) {
    out[out_size - 3] = 0.f;
    out[out_size - 2] = (float)N_USERS_C;
    out[out_size - 1] = (float)N_NODES_C;
  }
  int node = blockIdx.x * 4 + (threadIdx.x >> 6);
  if (node >= N_NODES_C) return;
  int lane = threadIdx.x & 63;
  int c0 = lane * 4;
  int beg = ptrn[node], end = ptrn[node + 1];
  float aldv = sane(ald[node]);
  float m = -1e30f;
  float wsum = 0.f, a0 = 0.f, a1 = 0.f, a2 = 0.f, a3 = 0.f;
  const unsigned short* hsu = (const unsigned short*)hs;
  float alsv_p = 0.f;
  ushort4 hv_p = {0, 0, 0, 0};
  int src_b = 0;
  if (beg < end) {
    int s0 = clampsrc(elist_src[beg]);
    alsv_p = als[s0];
    hv_p = *(const ushort4*)(hsu + (long)s0 * 256 + c0);
    if (beg + 1 < end) src_b = clampsrc(elist_src[beg + 1]);
  }
  for (int i = beg; i < end; i++) {
    float alsv = alsv_p;
    ushort4 hv = hv_p;
    if (i + 1 < end) {
      alsv_p = als[src_b];
      hv_p = *(const ushort4*)(hsu + (long)src_b * 256 + c0);
    }
    if (i + 2 < end)
      src_b = clampsrc(elist_src[i + 2]);
    float ev = sane(alsv) + aldv;
    ev = ev > 0.f ? ev : NEG_C * ev;
    float mnew = fmaxf(m, ev);
    float corr = __expf(m - mnew);
    float w = __expf(ev - mnew);
    m = mnew;
    wsum = wsum * corr + w;
    a0 = a0 * corr + w * bf2f(hv.x); a1 = a1 * corr + w * bf2f(hv.y);
    a2 = a2 * corr + w * bf2f(hv.z); a3 = a3 * corr + w * bf2f(hv.w);
  }
  float inv = 1.f / (wsum + 1e-16f);
  float4 v;
  v.x = a0 * inv + __bfloat162float(bias[c0 + 0]);
  v.y = a1 * inv + __bfloat162float(bias[c0 + 1]);
  v.z = a2 * inv + __bfloat162float(bias[c0 + 2]);
  v.w = a3 * inv + __bfloat162float(bias[c0 + 3]);
  v.x = fminf(fmaxf(v.x, -CLAMP_C), CLAMP_C);
  v.y = fminf(fmaxf(v.y, -CLAMP_C), CLAMP_C);
  v.z = fminf(fmaxf(v.z, -CLAMP_C), CLAMP_C);
  v.w = fminf(fmaxf(v.w, -CLAMP_C), CLAMP_C);
  *(float4*)(out + (long)node * 256 + c0) = v;
}

extern "C" void kernel_launch(void* const* d_in, const int* in_sizes, int n_in,
                              void* d_out, int out_size, void* d_ws, size_t ws_size,
                              hipStream_t stream) {
  const void* mov_x    = d_in[2];
  const int*  ei       = (const int*)d_in[3];
  const void* user_emb = d_in[4];
  const void* item_emb = d_in[5];

  char* ws = (char*)d_ws;
  size_t off = 0;
  auto alloc = [&](size_t bytes) -> void* {
    void* p = ws + off; off += (bytes + 255) / 256 * 256; return p;
  };
  int* flag   = (int*)alloc(4);
  __hip_bfloat16* Bt1 = (__hip_bfloat16*)alloc(272 * 192 * 2);
  __hip_bfloat16* Bt2 = (__hip_bfloat16*)alloc(272 * 256 * 2);
  __hip_bfloat16* W1t = (__hip_bfloat16*)alloc(128 * KPAD_C * 2);
  __hip_bfloat16* W2t = (__hip_bfloat16*)alloc(128 * 128 * 2);
  __hip_bfloat16* b1c = (__hip_bfloat16*)alloc(128 * 2);
  __hip_bfloat16* b2c = (__hip_bfloat16*)alloc(128 * 2);
  __hip_bfloat16* bg1 = (__hip_bfloat16*)alloc(256 * 2);
  __hip_bfloat16* bg2 = (__hip_bfloat16*)alloc(256 * 2);
  int* ptrn   = (int*)alloc((N_NODES_C + 1) * 4);
  int* deg    = (int*)alloc(N_NODES_C * 4);
  int* cursor = (int*)alloc(N_NODES_C * 4);
  int* bsum   = (int*)alloc(512 * 4);
  int* elist  = (int*)alloc(E_TOT_C * 4);
  float* als  = (float*)alloc((size_t)N_NODES_C * 8 * 4);
  float* ald  = (float*)alloc((size_t)N_NODES_C * 8 * 4);
  float* part = (float*)alloc((size_t)KSPLIT * N_ITEMS_C * 128 * 4);   // 40.96 MB
  __hip_bfloat16* x  = (__hip_bfloat16*)alloc((size_t)N_NODES_C * D_IN_C * 2); // 46.08 MB
  __hip_bfloat16* hs = (__hip_bfloat16*)alloc((size_t)N_NODES_C * HID_C * 2);  // 61.44 MB
  // d_out (f32, 122.88 MB) hosts h1 (bf16, dead before aggregate2) at byte 0.
  __hip_bfloat16* h1  = (__hip_bfloat16*)d_out;

  detect_dtype<<<1, 256, 0, stream>>>((const unsigned short*)user_emb, flag);

  PrepArgs pa;
  pa.ue = user_emb; pa.ie = item_emb;
  pa.gW1 = d_in[6];  pa.gb1 = d_in[7];  pa.gW2 = d_in[8];  pa.gb2 = d_in[9];
  pa.tW1 = d_in[10]; pa.tb1 = d_in[11]; pa.tW2 = d_in[12]; pa.tb2 = d_in[13];
  pa.Ws1 = d_in[14]; pa.Wd1 = d_in[15]; pa.as1 = d_in[16]; pa.ad1 = d_in[17]; pa.b1 = d_in[18];
  pa.Ws2 = d_in[19]; pa.Wd2 = d_in[20]; pa.as2 = d_in[21]; pa.ad2 = d_in[22]; pa.b2 = d_in[23];
  pa.x = x; pa.Bt1 = Bt1; pa.Bt2 = Bt2; pa.W1t = W1t; pa.W2t = W2t;
  pa.b1c = b1c; pa.b2c = b2c; pa.bg1 = bg1; pa.bg2 = bg2;
  pa.deg = deg; pa.cursor = cursor; pa.flag = flag;
  mega_prep<<<NB_PREP, 256, 0, stream>>>(pa);

  // [movie layer-1 K-split || gemm1 user blocks || deg_count] — all dep only on prep
  fused_stage3<<<NB_BIG, 256, 0, stream>>>(mov_x, flag, W1t, part,
                                           x, Bt1, hs, als, ald, ei, deg);
  // [movie layer-2 reduce || deg block sums]
  movie2_bsum<<<NB_KB, 256, 0, stream>>>(part, b1c, W2t, b2c,
                                         x + (long)N_USERS_C * D_IN_C, deg, bsum);
  bsum_scan<<<1, 512, 0, stream>>>(bsum, ptrn);
  deg_scan_final<<<NB_SCAN, 256, 0, stream>>>(deg, bsum, ptrn);

  // [gemm1 movie/mixed blocks || scatter_edges]
  gemm1mov_scatter<<<NB_S7, 256, 0, stream>>>(x, Bt1, hs, als, ald,
                                              ei, ptrn, cursor, elist);
  aggregate1<<<N_NODES_C / 4, 256, 0, stream>>>(ptrn, elist, als, ald, hs, bg1, h1);

  // layer 2
  gemm_fused<<<NB_GEMM, 256, 0, stream>>>(h1, Bt2, hs, als, ald, 256, 1, 256);
  aggregate2<<<N_NODES_C / 4, 256, 0, stream>>>(ptrn, elist, als, ald, hs, bg2,
                                                (float*)d_out, out_size);
}